// Round 1
// 300.858 us; speedup vs baseline: 1.0649x; 1.0649x over previous
//
#include <hip/hip_runtime.h>
#include <math.h>

#define NEG_BIG (-1e30f)

typedef __attribute__((ext_vector_type(8))) short short8;
typedef __attribute__((ext_vector_type(8))) _Float16 half8;
typedef __attribute__((ext_vector_type(4))) float floatx4;

__device__ __forceinline__ unsigned short f2bf(float x) {
    unsigned u = __float_as_uint(x);
    unsigned r = (u + 0x7fffu + ((u >> 16) & 1u)) >> 16;
    return (unsigned short)r;
}

__device__ __forceinline__ short f2h(float x) {
    _Float16 h = (_Float16)x;
    return __builtin_bit_cast(short, h);
}
__device__ __forceinline__ float h2f(short s) {
    return (float)__builtin_bit_cast(_Float16, s);
}

// ---------------- init winner = -1 ----------------
__global__ void k_init(int* __restrict__ w, int n) {
    int t = blockIdx.x * 256 + threadIdx.x;
    if (t < n) w[t] = -1;
}

// ---------------- prep: split W_atom (512x512, [k][n]) into 2 f16 planes laid out [n][k] ----------------
// low plane scaled by 2048 so residuals stay in f16 normal range
__global__ void k_prepWa(const float* __restrict__ W, short* __restrict__ H,
                         short* __restrict__ L) {
    int t = blockIdx.x * 256 + threadIdx.x;   // 262144
    int n = t >> 9, k = t & 511;
    float x = W[(size_t)k * 512 + n];
    short h = f2h(x);
    float r = (x - h2f(h)) * 2048.0f;
    H[t] = h;
    L[t] = f2h(r);
}

// ---------------- prep: W_bond (512x16 -> [h][k] bf16) ----------------
__global__ void k_prepWb(const float* __restrict__ Wb, short* __restrict__ Wbt) {
    int t = blockIdx.x * 256 + threadIdx.x;   // 8192
    int h = t >> 9, k = t & 511;
    Wbt[t] = (short)f2bf(Wb[(size_t)k * 16 + h]);
}

// ---------------- atoms GEMM via MFMA, fp32 emulated with f16x2 split, 3 products ----------------
// acc1 <- Ah*Bh ; acc2 <- Ah*Bl + Al*Bh (low planes pre-scaled x2048); out = acc1 + acc2/2048
// tile 128x128, BK=32; one block = one molecule (blockIdx.y), 4 n-tiles (blockIdx.x)
__global__ __launch_bounds__(256, 2) void k_atoms_mfma(
    const float* __restrict__ fA, const float* __restrict__ fAo,
    const int* __restrict__ a_scope,
    const short* __restrict__ WH, const short* __restrict__ WL,
    const float* __restrict__ bias, float* __restrict__ out, int Bmol)
{
    __shared__ short A_s[2][128 * 40];   // [plane][m][k] pad 40
    __shared__ short B_s[2][128 * 40];   // [plane][n][k] pad 40
    __shared__ int rs[128];

    const int tid = threadIdx.x;
    const int n0 = blockIdx.x * 128;
    const int mol = blockIdx.y;

    if (tid < 128) {
        int len = a_scope[2 * mol + 1];
        rs[tid] = (tid < len) ? (a_scope[2 * mol] + tid) : -1;
    }
    const int wid = tid >> 6, lane = tid & 63;
    const int wm = (wid >> 1) * 64, wn = (wid & 1) * 64;
    const int quad = lane >> 4, l16 = lane & 15;

    floatx4 acc1[4][4], acc2[4][4];
#pragma unroll
    for (int i = 0; i < 4; i++)
#pragma unroll
        for (int j = 0; j < 4; j++) {
            acc1[i][j] = (floatx4){0.f, 0.f, 0.f, 0.f};
            acc2[i][j] = (floatx4){0.f, 0.f, 0.f, 0.f};
        }

    const int ar = tid >> 1;           // 0..127 (row for A and n-row for B staging)
    const int ak = (tid & 1) * 16;     // 0 / 16
    __syncthreads();                   // rs ready
    const int asrc = rs[ar];

    for (int k0 = 0; k0 < 512; k0 += 32) {
        // ---- global loads (before barrier: overlap with previous compute) ----
        float x[16];
        if (asrc >= 0) {
            int kg = k0 + ak;
            const float* p = (kg < 256) ? (fA + (size_t)asrc * 256 + kg)
                                        : (fAo + (size_t)asrc * 256 + (kg - 256));
#pragma unroll
            for (int i = 0; i < 4; i++) {
                float4 v = ((const float4*)p)[i];
                x[i * 4 + 0] = v.x; x[i * 4 + 1] = v.y;
                x[i * 4 + 2] = v.z; x[i * 4 + 3] = v.w;
            }
        } else {
#pragma unroll
            for (int i = 0; i < 16; i++) x[i] = 0.f;
        }
        size_t goff = (size_t)(n0 + ar) * 512 + k0 + ak;
        short8 bh0 = *(const short8*)(WH + goff);
        short8 bh1 = *(const short8*)(WH + goff + 8);
        short8 bl0 = *(const short8*)(WL + goff);
        short8 bl1 = *(const short8*)(WL + goff + 8);

        // split A into f16 hi + scaled-lo
        short8 ah0, ah1, al0, al1;
#pragma unroll
        for (int i = 0; i < 8; i++) {
            short h = f2h(x[i]);
            float r = (x[i] - h2f(h)) * 2048.0f;
            ah0[i] = h; al0[i] = f2h(r);
        }
#pragma unroll
        for (int i = 0; i < 8; i++) {
            float xx = x[8 + i];
            short h = f2h(xx);
            float r = (xx - h2f(h)) * 2048.0f;
            ah1[i] = h; al1[i] = f2h(r);
        }

        __syncthreads();   // previous iteration's frag reads done
        const int abase = ar * 40 + ak;
        *(short8*)&A_s[0][abase] = ah0; *(short8*)&A_s[0][abase + 8] = ah1;
        *(short8*)&A_s[1][abase] = al0; *(short8*)&A_s[1][abase + 8] = al1;
        *(short8*)&B_s[0][abase] = bh0; *(short8*)&B_s[0][abase + 8] = bh1;
        *(short8*)&B_s[1][abase] = bl0; *(short8*)&B_s[1][abase + 8] = bl1;
        __syncthreads();

        half8 afh[4], afl[4];
#pragma unroll
        for (int ti = 0; ti < 4; ti++) {
            int off = (wm + ti * 16 + l16) * 40 + quad * 8;
            afh[ti] = *(const half8*)&A_s[0][off];
            afl[ti] = *(const half8*)&A_s[1][off];
        }
#pragma unroll
        for (int tj = 0; tj < 4; tj++) {
            int off = (wn + tj * 16 + l16) * 40 + quad * 8;
            half8 bh = *(const half8*)&B_s[0][off];
            half8 bl = *(const half8*)&B_s[1][off];
#pragma unroll
            for (int ti = 0; ti < 4; ti++) {
                acc1[ti][tj] = __builtin_amdgcn_mfma_f32_16x16x32_f16(afh[ti], bh, acc1[ti][tj], 0, 0, 0);
                acc2[ti][tj] = __builtin_amdgcn_mfma_f32_16x16x32_f16(afh[ti], bl, acc2[ti][tj], 0, 0, 0);
                acc2[ti][tj] = __builtin_amdgcn_mfma_f32_16x16x32_f16(afl[ti], bh, acc2[ti][tj], 0, 0, 0);
            }
        }
    }

    // epilogue: D col = lane&15, row = quad*4+reg  (m89-verified layout)
#pragma unroll
    for (int tj = 0; tj < 4; tj++) {
        int n = n0 + wn + tj * 16 + l16;
        float bv = bias[n];
#pragma unroll
        for (int ti = 0; ti < 4; ti++) {
#pragma unroll
            for (int r = 0; r < 4; r++) {
                int pos = wm + ti * 16 + quad * 4 + r;
                bool valid = rs[pos] >= 0;
                float v = valid ? (acc1[ti][tj][r] + 4.8828125e-4f * acc2[ti][tj][r] + bv) : 0.f;
                out[((size_t)pos * Bmol + mol) * 512 + n] = v;
            }
        }
    }
}

// ---------------- bonds GEMM via bf16 MFMA: 64 bonds/block, 16 heads, K=512 ----------------
__global__ __launch_bounds__(256) void k_bonds_mfma(
    const float* __restrict__ fB, const float* __restrict__ fBo,
    const short* __restrict__ Wbt, const float* __restrict__ bb_,
    float* __restrict__ bonds, int Nb)
{
    __shared__ short feat[64 * 136];  // [bond][k] pad 136, current BK=128 slice
    __shared__ short wb[16 * 512];    // [h][k] full K, chunk-swizzled by h

    const int tid = threadIdx.x;
    const int j0 = blockIdx.x * 64;

    for (int c = tid; c < 1024; c += 256) {
        int h = c >> 6, cc = c & 63;
        short8 v = *(const short8*)(Wbt + h * 512 + cc * 8);
        *(short8*)&wb[h * 512 + (((cc + h) & 63) * 8)] = v;
    }

    const int wid = tid >> 6, lane = tid & 63;
    const int quad = lane >> 4, l16 = lane & 15;
    floatx4 acc = (floatx4){0.f, 0.f, 0.f, 0.f};

    const int fr = tid >> 2;           // bond row 0..63
    const int fs = (tid & 3) * 32;     // k-seg
    const int j = j0 + fr;

    for (int k0 = 0; k0 < 512; k0 += 128) {
        float x[32];
        if (j < Nb) {
            const float* p = (k0 < 256) ? (fB + (size_t)j * 256 + k0 + fs)
                                        : (fBo + (size_t)j * 256 + (k0 - 256) + fs);
#pragma unroll
            for (int i = 0; i < 8; i++) {
                float4 v = ((const float4*)p)[i];
                x[i * 4 + 0] = v.x; x[i * 4 + 1] = v.y;
                x[i * 4 + 2] = v.z; x[i * 4 + 3] = v.w;
            }
        } else {
#pragma unroll
            for (int i = 0; i < 32; i++) x[i] = 0.f;
        }
        __syncthreads();
#pragma unroll
        for (int c = 0; c < 4; c++) {
            short8 s;
#pragma unroll
            for (int i = 0; i < 8; i++) s[i] = (short)f2bf(x[c * 8 + i]);
            *(short8*)&feat[fr * 136 + fs + c * 8] = s;
        }
        __syncthreads();
#pragma unroll
        for (int kk = 0; kk < 4; kk++) {
            short8 a = *(const short8*)&feat[(wid * 16 + l16) * 136 + kk * 32 + quad * 8];
            int kchunk = (k0 + kk * 32 + quad * 8) >> 3;
            short8 b = *(const short8*)&wb[l16 * 512 + (((kchunk + l16) & 63) * 8)];
            acc = __builtin_amdgcn_mfma_f32_16x16x32_bf16(a, b, acc, 0, 0, 0);
        }
    }
    float bv = bb_[l16];
#pragma unroll
    for (int r = 0; r < 4; r++) {
        int jj = j0 + wid * 16 + quad * 4 + r;
        if (jj < Nb) bonds[(size_t)jj * 16 + l16] = acc[r] + bv;
    }
}

// ---------------- scatter: last-update-wins via atomicMax on bond index ----------------
__global__ void k_scatter(const int* __restrict__ b2a, const int* __restrict__ b2revb,
                          const int* __restrict__ b_scope, int* __restrict__ winner,
                          int Nb, int Bmol)
{
    __shared__ int sb[128];
    int tid = threadIdx.x;
    if (tid < Bmol) sb[tid] = b_scope[2 * tid];
    __syncthreads();
    int j = blockIdx.x * 256 + tid;
    if (j >= Nb) return;
    int lo = 0, hi = Bmol;
    while (lo < hi) { int mid = (lo + hi) >> 1; if (sb[mid] <= j) lo = mid + 1; else hi = mid; }
    int mol = lo - 1; if (mol < 0) mol = 0;
    int p2 = b2a[j];
    int p1 = b2a[b2revb[j]];
    atomicMax(&winner[mol * 16384 + p1 * 128 + p2], j);
}

// ---------------- apairs fill: (B,16,128,128), NEG_BIG where p2 >= len ----------------
// register-transpose version: 16 dwordx4 loads instead of 64 scalar loads
__global__ __launch_bounds__(256) void k_apairs(
    const int* __restrict__ winner, const float* __restrict__ bonds,
    const int* __restrict__ a_scope, float* __restrict__ out, int Bmol)
{
    int t = blockIdx.x * 256 + threadIdx.x;
    int b = t >> 12;
    int p1 = (t >> 5) & 127;
    int p2q = t & 31;
    int len = a_scope[2 * b + 1];
    const int4 w = ((const int4*)winner)[t];

    int wi0 = w.x, wi1 = w.y, wi2 = w.z, wi3 = w.w;
    float rows[4][16];
#pragma unroll
    for (int c = 0; c < 16; c++) {
        rows[0][c] = 0.f; rows[1][c] = 0.f; rows[2][c] = 0.f; rows[3][c] = 0.f;
    }
    if (wi0 >= 0) {
        const float4* p = (const float4*)(bonds + (size_t)wi0 * 16);
#pragma unroll
        for (int c = 0; c < 4; c++) {
            float4 v = p[c];
            rows[0][4*c+0] = v.x; rows[0][4*c+1] = v.y; rows[0][4*c+2] = v.z; rows[0][4*c+3] = v.w;
        }
    }
    if (wi1 >= 0) {
        const float4* p = (const float4*)(bonds + (size_t)wi1 * 16);
#pragma unroll
        for (int c = 0; c < 4; c++) {
            float4 v = p[c];
            rows[1][4*c+0] = v.x; rows[1][4*c+1] = v.y; rows[1][4*c+2] = v.z; rows[1][4*c+3] = v.w;
        }
    }
    if (wi2 >= 0) {
        const float4* p = (const float4*)(bonds + (size_t)wi2 * 16);
#pragma unroll
        for (int c = 0; c < 4; c++) {
            float4 v = p[c];
            rows[2][4*c+0] = v.x; rows[2][4*c+1] = v.y; rows[2][4*c+2] = v.z; rows[2][4*c+3] = v.w;
        }
    }
    if (wi3 >= 0) {
        const float4* p = (const float4*)(bonds + (size_t)wi3 * 16);
#pragma unroll
        for (int c = 0; c < 4; c++) {
            float4 v = p[c];
            rows[3][4*c+0] = v.x; rows[3][4*c+1] = v.y; rows[3][4*c+2] = v.z; rows[3][4*c+3] = v.w;
        }
    }

    bool iv0 = (p2q * 4 + 0 >= len);
    bool iv1 = (p2q * 4 + 1 >= len);
    bool iv2 = (p2q * 4 + 2 >= len);
    bool iv3 = (p2q * 4 + 3 >= len);
    float* ob = out + ((size_t)b * 16 * 128 + p1) * 128 + p2q * 4;
#pragma unroll
    for (int h = 0; h < 16; h++) {
        float4 v;
        v.x = iv0 ? NEG_BIG : rows[0][h];
        v.y = iv1 ? NEG_BIG : rows[1][h];
        v.z = iv2 ? NEG_BIG : rows[2][h];
        v.w = iv3 ? NEG_BIG : rows[3][h];
        *(float4*)(ob + (size_t)h * 16384) = v;
    }
}

// ---------------- padding mask as float ----------------
__global__ void k_mask(const int* __restrict__ a_scope, float* __restrict__ out, int Bmol) {
    int t = blockIdx.x * 256 + threadIdx.x;
    if (t >= Bmol * 128) return;
    int b = t >> 7, p = t & 127;
    out[t] = (p >= a_scope[2 * b + 1]) ? 1.0f : 0.0f;
}

extern "C" void kernel_launch(void* const* d_in, const int* in_sizes, int n_in,
                              void* d_out, int out_size, void* d_ws, size_t ws_size,
                              hipStream_t stream)
{
    const float* f_atoms     = (const float*)d_in[0];
    const float* f_bonds     = (const float*)d_in[1];
    const float* f_atoms_out = (const float*)d_in[2];
    const float* f_bonds_out = (const float*)d_in[3];
    const int*   b2a         = (const int*)d_in[4];
    const int*   b2revb      = (const int*)d_in[5];
    const int*   a_scope     = (const int*)d_in[6];
    const int*   b_scope     = (const int*)d_in[7];
    const float* W_atom      = (const float*)d_in[9];
    const float* b_atom      = (const float*)d_in[10];
    const float* W_bond      = (const float*)d_in[11];
    const float* b_bond      = (const float*)d_in[12];

    const int Bmol = in_sizes[6] / 2;   // 128
    const int Nb   = in_sizes[4];

    char* ws = (char*)d_ws;
    size_t off = 0;
    float* bonds_ws = (float*)(ws + off); off += ((size_t)Nb * 16 * 4 + 255) & ~(size_t)255;
    int*   winner   = (int*)(ws + off);   off += (size_t)Bmol * 16384 * 4;
    short* WH       = (short*)(ws + off); off += 512 * 512 * 2;
    short* WL       = (short*)(ws + off); off += 512 * 512 * 2;
    short* Wbt      = (short*)(ws + off); off += 16 * 512 * 2;

    float* out_emb  = (float*)d_out;                                // (128, B, 512)
    float* out_ap   = out_emb + (size_t)128 * Bmol * 512;           // (B, 16, 128, 128)
    float* out_mask = out_ap + (size_t)Bmol * 16 * 128 * 128;       // (B, 128)

    const int ncell = Bmol * 16384;
    hipLaunchKernelGGL(k_prepWa, dim3(1024), dim3(256), 0, stream, W_atom, WH, WL);
    hipLaunchKernelGGL(k_prepWb, dim3(32), dim3(256), 0, stream, W_bond, Wbt);
    hipLaunchKernelGGL(k_init, dim3((ncell + 255) / 256), dim3(256), 0, stream, winner, ncell);
    hipLaunchKernelGGL(k_atoms_mfma, dim3(4, Bmol), dim3(256), 0, stream,
                       f_atoms, f_atoms_out, a_scope, WH, WL, b_atom, out_emb, Bmol);
    hipLaunchKernelGGL(k_bonds_mfma, dim3((Nb + 63) / 64), dim3(256), 0, stream,
                       f_bonds, f_bonds_out, Wbt, b_bond, bonds_ws, Nb);
    hipLaunchKernelGGL(k_scatter, dim3((Nb + 255) / 256), dim3(256), 0, stream,
                       b2a, b2revb, b_scope, winner, Nb, Bmol);
    hipLaunchKernelGGL(k_apairs, dim3(Bmol * 4096 / 256), dim3(256), 0, stream,
                       winner, bonds_ws, a_scope, out_ap, Bmol);
    hipLaunchKernelGGL(k_mask, dim3((Bmol * 128 + 255) / 256), dim3(256), 0, stream,
                       a_scope, out_mask, Bmol);
}